// Round 6
// baseline (76.966 us; speedup 1.0000x reference)
//
#include <hip/hip_runtime.h>

// RippleLinear: out[b,o] = sum_i amp[i,o] * sin(x[b,i]*freq[i,o] + ph[i,o]) + bias0[o]
//   x:      (2048, 256) f32   (16*128 rows)
//   weight: (256, 256, 2) f32  -> amp = w[i][o][0], freq = w[i][o][1]
//   bias:   (257, 256) f32     -> bias0 = bias[0][:], ph[i][o] = bias[1+i][o]
//   out:    (2048, 256) f32
//
// R5 -> R6: R5 kernel ~27us vs ~11us issue floor -> ~55% SIMD stall at 16
// waves/CU. Weight re-stream multiplicity = #row-blocks only, so o-splitting
// adds waves TRAFFIC-FREE (R3's mistake was row-splitting). Grid 1024 =
// 256 row-blocks x 4 o-splits, block (32 opairs x 16 igroups) = 512 thr,
// 4 blocks/CU = 32 waves/CU (100% wave cap). Wave halves hold adjacent
// i-groups -> __shfl_down(32) merge, then one-step LDS reduction (14 KB;
// 22 KB total -> 4 blocks/CU fits). launch_bounds(512,8) caps VGPR at 64.

constexpr int IN_F   = 256;
constexpr int OUT_F  = 256;
constexpr int BROWS  = 2048;
constexpr int BTILE  = 8;                 // batch rows per block
constexpr int ISPLIT = 16;                // i-groups per block (half-wave each)
constexpr int ICHUNK = IN_F / ISPLIT;     // 16 i per group
constexpr int OPAIRS = 32;                // o-pairs per block (= 64 o columns)
constexpr int OSPLIT = 4;                 // o-splits across blocks

#define INV2PI 0.15915494309189535f

__global__ __launch_bounds__(OPAIRS * ISPLIT, 8) void ripple_kernel(
    const float* __restrict__ x,       // (BROWS, IN_F)
    const float* __restrict__ weight,  // (IN_F, OUT_F, 2)
    const float* __restrict__ bias,    // (IN_F+1, OUT_F)
    float* __restrict__ out)           // (BROWS, OUT_F)
{
    const int tx = threadIdx.x;           // 0..31: o-pair lane
    const int g  = threadIdx.y;           // 0..15: i-group (half-wave)
    const int ob = blockIdx.x & (OSPLIT - 1);   // o-quarter
    const int bb = blockIdx.x >> 2;             // row-block
    const int b0 = bb * BTILE;
    const int oc = ob * OPAIRS + tx;      // global o-pair index 0..127

    __shared__ __align__(16) float xs_t[IN_F * BTILE];           // 8 KB, [i*8+r] = x/(2pi)
    __shared__ float2 red[ISPLIT / 2 - 1][BTILE][OPAIRS];        // 14 KB

    // --- stage x-tile transposed+prescaled. thread t -> (i4 = t>>3, r = t&7):
    //     global: 8x128B segments/wave (once); LDS stores 8-way conflict only.
    {
        const int t  = g * OPAIRS + tx;   // 0..511
        const int r  = t & 7;
        const int i4 = t >> 3;            // 0..63
        const float4 v = ((const float4*)x)[(b0 + r) * (IN_F / 4) + i4];
        xs_t[(4 * i4 + 0) * BTILE + r] = v.x * INV2PI;
        xs_t[(4 * i4 + 1) * BTILE + r] = v.y * INV2PI;
        xs_t[(4 * i4 + 2) * BTILE + r] = v.z * INV2PI;
        xs_t[(4 * i4 + 3) * BTILE + r] = v.w * INV2PI;
    }
    __syncthreads();

    float acc0[BTILE], acc1[BTILE];
#pragma unroll
    for (int r = 0; r < BTILE; ++r) { acc0[r] = 0.0f; acc1[r] = 0.0f; }

    const float4* __restrict__ wq  = (const float4*)weight;  // (amp0,freq0,amp1,freq1)
    const float2* __restrict__ ph2 = (const float2*)bias;    // phase pairs

    const int i0 = g * ICHUNK;
#pragma unroll 2
    for (int ii = 0; ii < ICHUNK; ++ii) {
        const int i = i0 + ii;
        const float4 w = wq[i * (OUT_F / 2) + oc];           // 2x512B segments/wave
        const float2 p = ph2[(i + 1) * (OUT_F / 2) + oc];
        const float px = p.x * INV2PI;
        const float py = p.y * INV2PI;
        const float4 xa = *(const float4*)&xs_t[i * BTILE];      // rows 0..3
        const float4 xb = *(const float4*)&xs_t[i * BTILE + 4];  // rows 4..7
        const float xv[BTILE] = {xa.x, xa.y, xa.z, xa.w, xb.x, xb.y, xb.z, xb.w};
#pragma unroll
        for (int r = 0; r < BTILE; ++r) {
            acc0[r] += w.x * __builtin_amdgcn_sinf(fmaf(xv[r], w.y, px));
            acc1[r] += w.z * __builtin_amdgcn_sinf(fmaf(xv[r], w.w, py));
        }
    }

    // --- merge the wave's two halves (adjacent i-groups, same oc) in-register
#pragma unroll
    for (int r = 0; r < BTILE; ++r) {
        acc0[r] += __shfl_down(acc0[r], 32);
        acc1[r] += __shfl_down(acc1[r], 32);
    }

    // --- one-step LDS reduction across the 8 waves ---
    const int wv = g >> 1;                // wave index 0..7 (valid in lanes with even g)
    if ((g & 1) == 0 && wv > 0) {
#pragma unroll
        for (int r = 0; r < BTILE; ++r) red[wv - 1][r][tx] = make_float2(acc0[r], acc1[r]);
    }
    __syncthreads();
    if (g == 0) {                          // lanes 0..31 of wave 0
        const float2 bo = ph2[oc];         // bias row 0
#pragma unroll
        for (int r = 0; r < BTILE; ++r) {
            float s0 = acc0[r], s1 = acc1[r];
#pragma unroll
            for (int k = 0; k < ISPLIT / 2 - 1; ++k) {
                const float2 t = red[k][r][tx];
                s0 += t.x; s1 += t.y;
            }
            ((float2*)out)[(b0 + r) * (OUT_F / 2) + oc] = make_float2(s0 + bo.x, s1 + bo.y);
        }
    }
}

extern "C" void kernel_launch(void* const* d_in, const int* in_sizes, int n_in,
                              void* d_out, int out_size, void* d_ws, size_t ws_size,
                              hipStream_t stream) {
    const float* x      = (const float*)d_in[0];
    const float* weight = (const float*)d_in[1];
    const float* bias   = (const float*)d_in[2];
    float* out          = (float*)d_out;

    dim3 grid((BROWS / BTILE) * OSPLIT);   // 1024 blocks -> 4 blocks/CU
    dim3 block(OPAIRS, ISPLIT);            // 512 threads = 8 waves
    ripple_kernel<<<grid, block, 0, stream>>>(x, weight, bias, out);
}